// Round 4
// baseline (76.638 us; speedup 1.0000x reference)
//
#include <hip/hip_runtime.h>
#include <stdint.h>

typedef float f32x16 __attribute__((ext_vector_type(16)));
typedef short bf16x8 __attribute__((ext_vector_type(8)));
typedef uint32_t u32;
typedef uint32_t u32x4 __attribute__((ext_vector_type(4)));

#define SIZE 784
#define NLBL 10
#define LABEL_SITE 392
#define BATCH 128
// precomputed fragment array: u32 elements per array
#define PRE_ELEMS (SIZE * 2 * 64 * 4)

// ---------- helpers ----------

// pack 2 fp32 -> 2 bf16 (RNE), elem a -> low16, elem b -> high16
__device__ inline u32 cvt_pk(float a, float b) {
  u32 r;
  asm("v_cvt_pk_bf16_f32 %0, %1, %2" : "=v"(r) : "v"(a), "v"(b));
  return r;
}
__device__ inline float lo16f(u32 h) { return __uint_as_float(h << 16); }
__device__ inline float hi16f(u32 h) { return __uint_as_float(h & 0xffff0000u); }

// Split 8 fp32 (j-order) into packed bf16 hi/lo fragments using RNE.
__device__ inline void split_pack(const float s[8], u32 hi[4], u32 lo[4]) {
#pragma unroll
  for (int p = 0; p < 4; ++p) {
    u32 h = cvt_pk(s[2 * p], s[2 * p + 1]);
    hi[p] = h;
    lo[p] = cvt_pk(s[2 * p] - lo16f(h), s[2 * p + 1] - hi16f(h));
  }
}

__device__ inline f32x16 mfma_bb(const u32 (&a)[4], const u32 (&b)[4], f32x16 c) {
  union U { u32 u[4]; bf16x8 v; };
  U A, B;
#pragma unroll
  for (int i = 0; i < 4; ++i) { A.u[i] = a[i]; B.u[i] = b[i]; }
  return __builtin_amdgcn_mfma_f32_32x32x16_bf16(A.v, B.v, c, 0, 0, 0);
}
__device__ inline f32x16 mfma_v4(u32x4 a, const u32 (&b)[4], f32x16 c) {
  union UA { u32x4 u; bf16x8 v; } A; A.u = a;
  union UB { u32 u[4]; bf16x8 v; } B;
#pragma unroll
  for (int i = 0; i < 4; ++i) B.u[i] = b[i];
  return __builtin_amdgcn_mfma_f32_32x32x16_bf16(A.v, B.v, c, 0, 0, 0);
}

// Identity matrix in C/D fragment layout:
// row = (reg&3) + 8*(reg>>2) + 4*(lane>>5), col = lane&31
__device__ inline f32x16 ident_acc(int lane) {
  const int gam = lane & 31, hib = lane >> 5;
  f32x16 a;
#pragma unroll
  for (int reg = 0; reg < 16; ++reg) {
    int rho = (reg & 3) + 8 * (reg >> 2) + 4 * hib;
    a[reg] = (rho == gam) ? 1.0f : 0.0f;
  }
  return a;
}

// Build B-operand hi/lo frags for k-half t from acc (C/D layout), in-register.
// Reformulated: 1 shuffle + 3 selects per reg pair (was 2 shuffles + 2 selects).
__device__ inline void build_b(const f32x16& acc, int hib, int t,
                               u32 (&Bh)[4], u32 (&Bl)[4]) {
  float slot[8];
#pragma unroll
  for (int j = 0; j < 4; ++j) {
    const int q1 = 8 * t + j, q2 = q1 + 4;
    float z = hib ? acc[q1] : acc[q2];   // value the lane^32 partner needs
    float wv = __shfl_xor(z, 32, 64);
    slot[j]     = hib ? wv : acc[q1];
    slot[j + 4] = hib ? acc[q2] : wv;
  }
  split_pack(slot, Bh, Bl);
}

// One generic chain step X <- A*X with A given as hi/lo frags (phase 2).
__device__ inline f32x16 chain_step(const u32 (&Ah)[2][4], const u32 (&Al)[2][4],
                                    f32x16 acc, int hib) {
  f32x16 r;
#pragma unroll
  for (int q = 0; q < 16; ++q) r[q] = 0.0f;
#pragma unroll
  for (int t = 0; t < 2; ++t) {
    u32 Bh[4], Bl[4];
    build_b(acc, hib, t, Bh, Bl);
    r = mfma_bb(Al[t], Bh, r);
    r = mfma_bb(Ah[t], Bl, r);
    r = mfma_bb(Ah[t], Bh, r);
  }
  return r;
}

// Store acc (C/D layout) into A-fragment layout:
// Y[rho][gam] -> flat[h*512 + (rho + 32*((gam>>3)&1))*8 + (gam&7)], h = gam>>4
__device__ inline void store_afrag(float* dst, f32x16 acc, int lane) {
  const int gam = lane & 31, hib = lane >> 5;
  const int h = gam >> 4, j = gam & 7, b5 = (gam >> 3) & 1;
#pragma unroll
  for (int reg = 0; reg < 16; ++reg) {
    int rho = (reg & 3) + 8 * (reg >> 2) + 4 * hib;
    int lp = rho + 32 * b5;
    dst[h * 512 + lp * 8 + j] = acc[reg];
  }
}

__device__ inline void load_split_afrag(const float* src, int lane,
                                        u32 (&Ah)[2][4], u32 (&Al)[2][4]) {
#pragma unroll
  for (int h = 0; h < 2; ++h) {
    const float4* p = (const float4*)(src + h * 512 + lane * 8);
    float4 q0 = p[0], q1 = p[1];
    float v[8] = {q0.x, q0.y, q0.z, q0.w, q1.x, q1.y, q1.z, q1.w};
    split_pack(v, Ah[h], Al[h]);
  }
}

// ---------- phase 0: precompute bf16 hi/lo A-fragments of c0 and d=c1-c0 ----
// task = s*2 + t; one wave per task; lane writes 4 packed u32 per array.
__global__ __launch_bounds__(256) void mps_precomp(const float* __restrict__ core,
                                                   u32* __restrict__ pc0h,
                                                   u32* __restrict__ pc0l,
                                                   u32* __restrict__ pdh,
                                                   u32* __restrict__ pdl) {
  const int tid = threadIdx.x;
  const int w = tid >> 6, lane = tid & 63;
  const int task = blockIdx.x * 4 + w;       // 0..1567
  const int s = task >> 1, t = task & 1;
  const int r = lane & 31, hib = lane >> 5;
  const float* cs = core + (size_t)s * 2048 + r;
  u32 wc0h[4], wc0l[4], wdh[4], wdl[4];
#pragma unroll
  for (int p = 0; p < 4; ++p) {
    const int k0 = 16 * t + 8 * hib + 2 * p;
    float a0 = cs[k0 * 64],       a1 = cs[(k0 + 1) * 64];
    float b0 = cs[k0 * 64 + 32],  b1 = cs[(k0 + 1) * 64 + 32];
    float d0 = b0 - a0, d1 = b1 - a1;
    u32 h = cvt_pk(a0, a1);
    wc0h[p] = h;
    wc0l[p] = cvt_pk(a0 - lo16f(h), a1 - hi16f(h));
    u32 gg = cvt_pk(d0, d1);
    wdh[p] = gg;
    wdl[p] = cvt_pk(d0 - lo16f(gg), d1 - hi16f(gg));
  }
  const size_t base = ((size_t)task * 64 + lane) * 4;
  *(u32x4*)(pc0h + base) = *(u32x4*)wc0h;
  *(u32x4*)(pc0l + base) = *(u32x4*)wc0l;
  *(u32x4*)(pdh  + base) = *(u32x4*)wdh;
  *(u32x4*)(pdl  + base) = *(u32x4*)wdl;
}

// ---------- phase 1: per-segment chain products ----------
// grid = nseg*32 blocks x 4 waves; wave -> (segment g, batch item bi).
// X <- c0*X + x*(d*X); site order ci -> s=(392+ci)%784 (cyclic trick).
__global__ __launch_bounds__(256, 4) void mps_phase1(
    const float* __restrict__ input,
    const u32* __restrict__ pc0h, const u32* __restrict__ pc0l,
    const u32* __restrict__ pdh,  const u32* __restrict__ pdl,
    float* __restrict__ wsA, int nseg, int seglen) {
  const int tid = threadIdx.x;
  const int w = tid >> 6, lane = tid & 63;
  const int hib = lane >> 5;
  const int g = blockIdx.x % nseg, c = blockIdx.x / nseg;
  const int bi = c * 4 + w;

  f32x16 acc = ident_acc(lane);
  f32x16 z16;
#pragma unroll
  for (int q = 0; q < 16; ++q) z16[q] = 0.0f;

  const int ci0 = g * seglen;
  for (int i = 0; i < seglen; ++i) {
    int s = LABEL_SITE + ci0 + i;
    if (s >= SIZE) s -= SIZE;
    const float x = input[(size_t)bi * SIZE + s];
    f32x16 rc = z16, rd = z16;
#pragma unroll
    for (int t = 0; t < 2; ++t) {
      const size_t base = ((size_t)(s * 2 + t) * 64 + lane) * 4;
      u32x4 Ac0h = *(const u32x4*)(pc0h + base);
      u32x4 Ac0l = *(const u32x4*)(pc0l + base);
      u32x4 Adh  = *(const u32x4*)(pdh + base);
      u32x4 Adl  = *(const u32x4*)(pdl + base);
      u32 Bh[4], Bl[4];
      build_b(acc, hib, t, Bh, Bl);
      rd = mfma_v4(Adl, Bh, rd);
      rd = mfma_v4(Adh, Bl, rd);
      rd = mfma_v4(Adh, Bh, rd);
      rc = mfma_v4(Ac0l, Bh, rc);
      rc = mfma_v4(Ac0h, Bl, rc);
      rc = mfma_v4(Ac0h, Bh, rc);
    }
#pragma unroll
    for (int q = 0; q < 16; ++q) acc[q] = fmaf(x, rd[q], rc[q]);
  }
  store_afrag(wsA + ((size_t)bi * nseg + g) * 1024, acc, lane);
}

// ---------- phase 2a: combine GG consecutive segment products ----------
// 896 waves: wave wid -> bi = wid&127, gg = wid>>7 (7 groups of GG segments)
__global__ __launch_bounds__(256) void mps_phase2a(const float* __restrict__ wsA,
                                                   float* __restrict__ wsB,
                                                   int nseg, int GG) {
  const int tid = threadIdx.x;
  const int w = tid >> 6, lane = tid & 63;
  const int wid = blockIdx.x * 4 + w;
  const int bi = wid & 127, gg = wid >> 7;
  f32x16 acc = ident_acc(lane);
  for (int g = gg * GG; g < gg * GG + GG; ++g) {
    u32 Ah[2][4], Al[2][4];
    load_split_afrag(wsA + ((size_t)bi * nseg + g) * 1024, lane, Ah, Al);
    acc = chain_step(Ah, Al, acc, lane >> 5);
  }
  store_afrag(wsB + ((size_t)bi * 7 + gg) * 1024, acc, lane);
}

// ---------- phase 2b: final combine (7 groups) + trace epilogue ----------
// acc ends as W^T in C/D layout; out[b,l] = sum T[rho][l][gam]*W^T[rho][gam]
__global__ __launch_bounds__(256) void mps_phase2b(const float* __restrict__ wsB,
                                                   const float* __restrict__ label,
                                                   float* __restrict__ out) {
  const int tid = threadIdx.x;
  const int w = tid >> 6, lane = tid & 63;
  const int bi = blockIdx.x * 4 + w;
  const int gam = lane & 31, hib = lane >> 5;
  f32x16 acc = ident_acc(lane);
  for (int gg = 0; gg < 7; ++gg) {
    u32 Ah[2][4], Al[2][4];
    load_split_afrag(wsB + ((size_t)bi * 7 + gg) * 1024, lane, Ah, Al);
    acc = chain_step(Ah, Al, acc, hib);
  }
  float part[NLBL];
#pragma unroll
  for (int l = 0; l < NLBL; ++l) part[l] = 0.0f;
#pragma unroll
  for (int reg = 0; reg < 16; ++reg) {
    const int rho = (reg & 3) + 8 * (reg >> 2) + 4 * hib;
    const float wv = acc[reg];
    const float* tp = label + rho * (NLBL * 32) + gam;
#pragma unroll
    for (int l = 0; l < NLBL; ++l) part[l] = fmaf(tp[l * 32], wv, part[l]);
  }
#pragma unroll
  for (int l = 0; l < NLBL; ++l) {
#pragma unroll
    for (int mask = 32; mask >= 1; mask >>= 1)
      part[l] += __shfl_xor(part[l], mask, 64);
  }
  if (lane == 0) {
#pragma unroll
    for (int l = 0; l < NLBL; ++l) out[bi * NLBL + l] = part[l];
  }
}

extern "C" void kernel_launch(void* const* d_in, const int* in_sizes, int n_in,
                              void* d_out, int out_size, void* d_ws, size_t ws_size,
                              hipStream_t stream) {
  const float* input = (const float*)d_in[0];  // [128,784]
  const float* core  = (const float*)d_in[1];  // [784,32,2,32]
  const float* label = (const float*)d_in[2];  // [32,10,32]
  float* out = (float*)d_out;                  // [128,10]

  // workspace: [c0h | c0l | dh | dl | wsA | wsB]
  u32* pc0h = (u32*)d_ws;
  u32* pc0l = pc0h + PRE_ELEMS;
  u32* pdh  = pc0l + PRE_ELEMS;
  u32* pdl  = pdh + PRE_ELEMS;
  float* wsA = (float*)(pdl + PRE_ELEMS);

  // need (4*PRE + 128*nseg*1024 + 128*7*1024)*4 bytes
  const size_t need112 = ((size_t)4 * PRE_ELEMS + (size_t)BATCH * 112 * 1024 +
                          (size_t)BATCH * 7 * 1024) * 4;
  const int nseg = (ws_size >= need112) ? 112 : 56;
  const int seglen = SIZE / nseg;
  const int GG = nseg / 7;
  float* wsB = wsA + (size_t)BATCH * nseg * 1024;

  mps_precomp<<<dim3(392), dim3(256), 0, stream>>>(core, pc0h, pc0l, pdh, pdl);
  mps_phase1<<<dim3(nseg * 32), dim3(256), 0, stream>>>(input, pc0h, pc0l, pdh, pdl,
                                                        wsA, nseg, seglen);
  mps_phase2a<<<dim3(224), dim3(256), 0, stream>>>(wsA, wsB, nseg, GG);
  mps_phase2b<<<dim3(32), dim3(256), 0, stream>>>(wsB, label, out);
}